// Round 1
// baseline (118.026 us; speedup 1.0000x reference)
//
#include <hip/hip_runtime.h>
#include <hip/hip_bf16.h>

typedef __attribute__((ext_vector_type(8))) short short8;
typedef __attribute__((ext_vector_type(4))) float f32x4;

#define MFMA16(A, B, C) __builtin_amdgcn_mfma_f32_16x16x32_bf16((A), (B), (C), 0, 0, 0)

__device__ __forceinline__ unsigned short bfbits(float f) {
  return __builtin_bit_cast(unsigned short, (__bf16)f);
}

constexpr int Mn = 2048;
constexpr int Dn = 64;
constexpr int LIMn = 2048;
constexpr int BM = 64;
constexpr int BL = 64;
constexpr int ESTRIDE = 84;  // 80 cols used; 84 to de-correlate banks

__launch_bounds__(256, 2)
__global__ void stair_attn(const float* __restrict__ Qg,
                           const float* __restrict__ Kg,
                           const float* __restrict__ Vg,
                           const float* __restrict__ PEg,
                           float* __restrict__ Og) {
  // LDS: 8KB + 8KB + 16KB + 21KB + 8KB = ~61KB  (<= 64KB static limit)
  __shared__ __align__(16) unsigned short Kb[64 * 64];   // [l][d] bf16, swz
  __shared__ __align__(16) unsigned short Vt[64 * 64];   // [d][l] bf16, swz
  __shared__ __align__(16) unsigned short Pb[128 * 64];  // [c][d] bf16, swz
  __shared__ __align__(16) float Elds[4 * 16 * ESTRIDE]; // per-wave E band
  __shared__ __align__(16) unsigned short Plds[4 * 16 * 64]; // per-wave P, swz

  const int tid = threadIdx.x;
  const int w = tid >> 6;        // wave 0..3
  const int lane = tid & 63;
  const int g = lane >> 4;       // k-group 0..3
  const int q15 = lane & 15;

  const int bid = blockIdx.x;
  const int bh = bid & 15;
  const int jid = bid >> 4;                       // 0..31
  const int mt = (jid < 16) ? (2 * jid) : (63 - 2 * jid); // load-balanced pairing
  const int m0 = mt * BM;

  const float* Qb = Qg + (size_t)bh * Mn * Dn;
  const float* Kbase = Kg + (size_t)bh * Mn * Dn;
  const float* Vbase = Vg + (size_t)bh * Mn * Dn;
  float* Ob = Og + (size_t)bh * Mn * Dn;

  // ---- Q A-fragments, kept in registers for the whole kernel.
  // A layout (16x16x32): row = lane&15, k = (lane>>4)*8 + j (contig 8), k-step s adds 32.
  short8 aq[2];
  {
    const float* qp = Qb + (size_t)(m0 + 16 * w + q15) * Dn;
#pragma unroll
    for (int s = 0; s < 2; ++s) {
      const float4* p = (const float4*)(qp + s * 32 + g * 8);
      float4 f0 = p[0], f1 = p[1];
      short8 a;
      a[0] = (short)bfbits(f0.x); a[1] = (short)bfbits(f0.y);
      a[2] = (short)bfbits(f0.z); a[3] = (short)bfbits(f0.w);
      a[4] = (short)bfbits(f1.x); a[5] = (short)bfbits(f1.y);
      a[6] = (short)bfbits(f1.z); a[7] = (short)bfbits(f1.w);
      aq[s] = a;
    }
  }

  float mrun[4], lrun[4];
  f32x4 o[4] = {};
#pragma unroll
  for (int r = 0; r < 4; ++r) { mrun[r] = -1e30f; lrun[r] = 0.0f; }

  const int ntiles = mt + 1;
  const int dso = g * 8;

  for (int t = 0; t < ntiles; ++t) {
    const int l0 = t * BL;
    __syncthreads();  // previous tile's compute done before restaging

    // ---- stage K tile: thread -> (row l = tid>>2, 16-col chunk)
    {
      const int l = tid >> 2;
      const int dq = (tid & 3) * 16;
      const float* kp = Kbase + (size_t)(l0 + l) * Dn + dq;
      short8 u0, u1;
      {
        float4 f = ((const float4*)kp)[0];
        u0[0]=(short)bfbits(f.x); u0[1]=(short)bfbits(f.y); u0[2]=(short)bfbits(f.z); u0[3]=(short)bfbits(f.w);
        f = ((const float4*)kp)[1];
        u0[4]=(short)bfbits(f.x); u0[5]=(short)bfbits(f.y); u0[6]=(short)bfbits(f.z); u0[7]=(short)bfbits(f.w);
        f = ((const float4*)kp)[2];
        u1[0]=(short)bfbits(f.x); u1[1]=(short)bfbits(f.y); u1[2]=(short)bfbits(f.z); u1[3]=(short)bfbits(f.w);
        f = ((const float4*)kp)[3];
        u1[4]=(short)bfbits(f.x); u1[5]=(short)bfbits(f.y); u1[6]=(short)bfbits(f.z); u1[7]=(short)bfbits(f.w);
      }
      const int swz = (l & 7) << 3;
      *(short8*)&Kb[(l * 64 + dq) ^ swz] = u0;
      *(short8*)&Kb[(l * 64 + dq + 8) ^ swz] = u1;
    }

    // ---- stage V tile transposed: lane = row, wave = 16-col chunk
    {
      const int lrow = lane;
      const int ds = w * 16;
      const float* vp = Vbase + (size_t)(l0 + lrow) * Dn + ds;
#pragma unroll
      for (int i = 0; i < 4; ++i) {
        float4 f = ((const float4*)vp)[i];
        int c0 = ds + 4 * i;
        Vt[((c0 + 0) * 64 + lrow) ^ (((c0 + 0) & 7) << 3)] = bfbits(f.x);
        Vt[((c0 + 1) * 64 + lrow) ^ (((c0 + 1) & 7) << 3)] = bfbits(f.y);
        Vt[((c0 + 2) * 64 + lrow) ^ (((c0 + 2) & 7) << 3)] = bfbits(f.z);
        Vt[((c0 + 3) * 64 + lrow) ^ (((c0 + 3) & 7) << 3)] = bfbits(f.w);
      }
    }

    // ---- stage PE band transposed: Pb[c][d] = PE[d][cb + c], clamped
    {
      const int d = lane;
      const int cc = w * 32;
      const int cb = (2048 - BM) - m0 + l0;  // >= 0 always
      const float* pp = PEg + (size_t)d * LIMn + (cb + cc);
      if (cb + cc + 31 < LIMn) {
#pragma unroll
        for (int i = 0; i < 8; ++i) {
          float4 f = ((const float4*)pp)[i];
          int c0 = cc + 4 * i;
          Pb[((c0 + 0) * 64 + d) ^ (((c0 + 0) & 7) << 3)] = bfbits(f.x);
          Pb[((c0 + 1) * 64 + d) ^ (((c0 + 1) & 7) << 3)] = bfbits(f.y);
          Pb[((c0 + 2) * 64 + d) ^ (((c0 + 2) & 7) << 3)] = bfbits(f.z);
          Pb[((c0 + 3) * 64 + d) ^ (((c0 + 3) & 7) << 3)] = bfbits(f.w);
        }
      } else {
        for (int i = 0; i < 32; ++i) {
          int cabs = cb + cc + i;
          float f = (cabs < LIMn) ? pp[i] : 0.0f;
          int c0 = cc + i;
          Pb[(c0 * 64 + d) ^ ((c0 & 7) << 3)] = bfbits(f);
        }
      }
    }
    __syncthreads();

    // ---- QK^T: S_content (16x64 per wave), 8 MFMA
    f32x4 qk[4] = {};
#pragma unroll
    for (int s = 0; s < 2; ++s) {
#pragma unroll
      for (int nt = 0; nt < 4; ++nt) {
        int l = nt * 16 + q15;
        short8 b = *(short8*)&Kb[(l * 64 + s * 32 + dso) ^ ((l & 7) << 3)];
        qk[nt] = MFMA16(aq[s], b, qk[nt]);
      }
    }

    // ---- E band: per-wave 16 x 80 slice (n-tiles ntb..ntb+4), 10 MFMA
    f32x4 ev[5] = {};
    const int ntb = 3 - w;
#pragma unroll
    for (int s = 0; s < 2; ++s) {
#pragma unroll
      for (int u5 = 0; u5 < 5; ++u5) {
        int c = (ntb + u5) * 16 + q15;
        short8 b = *(short8*)&Pb[(c * 64 + s * 32 + dso) ^ ((c & 7) << 3)];
        ev[u5] = MFMA16(aq[s], b, ev[u5]);
      }
    }
    // spill E to per-wave LDS (C/D layout -> rows)
    float* Ew = Elds + w * 16 * ESTRIDE;
#pragma unroll
    for (int u5 = 0; u5 < 5; ++u5)
#pragma unroll
      for (int r = 0; r < 4; ++r)
        Ew[(g * 4 + r) * ESTRIDE + u5 * 16 + q15] = ev[u5][r];

    // ---- gather + mask + scale (local E col = 15 - row + li)
    const bool diag = (t == ntiles - 1);
    float sv[4][4];
#pragma unroll
    for (int nt = 0; nt < 4; ++nt) {
      int li = nt * 16 + q15;
#pragma unroll
      for (int r = 0; r < 4; ++r) {
        int rw = g * 4 + r;
        float eread = Ew[rw * ESTRIDE + (15 - rw + li)];
        bool masked = diag && (li > (16 * w + rw));  // l0==m0 on diagonal tile
        sv[nt][r] = masked ? -1e30f : (qk[nt][r] + eread) * 0.125f;
      }
    }

    // ---- online softmax (rows live in 16 lanes sharing lane>>4)
    float mnew[4], alpha[4];
#pragma unroll
    for (int r = 0; r < 4; ++r) {
      float mx = fmaxf(fmaxf(sv[0][r], sv[1][r]), fmaxf(sv[2][r], sv[3][r]));
      mx = fmaxf(mx, __shfl_xor(mx, 1));
      mx = fmaxf(mx, __shfl_xor(mx, 2));
      mx = fmaxf(mx, __shfl_xor(mx, 4));
      mx = fmaxf(mx, __shfl_xor(mx, 8));
      float mn = fmaxf(mrun[r], mx);
      alpha[r] = exp2f((mrun[r] - mn) * 1.44269504f);
      mnew[r] = mn;
      mrun[r] = mn;
    }
    float pexp[4][4];
#pragma unroll
    for (int nt = 0; nt < 4; ++nt)
#pragma unroll
      for (int r = 0; r < 4; ++r)
        pexp[nt][r] = exp2f((sv[nt][r] - mnew[r]) * 1.44269504f);
#pragma unroll
    for (int r = 0; r < 4; ++r) {
      float sum = (pexp[0][r] + pexp[1][r]) + (pexp[2][r] + pexp[3][r]);
      sum += __shfl_xor(sum, 1);
      sum += __shfl_xor(sum, 2);
      sum += __shfl_xor(sum, 4);
      sum += __shfl_xor(sum, 8);
      lrun[r] = lrun[r] * alpha[r] + sum;
      o[0][r] *= alpha[r];
      o[1][r] *= alpha[r];
      o[2][r] *= alpha[r];
      o[3][r] *= alpha[r];
    }

    // ---- P (C/D layout) -> per-wave LDS -> A-fragments
    unsigned short* Pw = Plds + w * 16 * 64;
#pragma unroll
    for (int nt = 0; nt < 4; ++nt)
#pragma unroll
      for (int r = 0; r < 4; ++r) {
        int rw = g * 4 + r;
        Pw[(rw * 64 + nt * 16 + q15) ^ ((rw & 7) << 3)] = bfbits(pexp[nt][r]);
      }
    short8 pa[2];
#pragma unroll
    for (int s = 0; s < 2; ++s)
      pa[s] = *(short8*)&Pw[(q15 * 64 + s * 32 + dso) ^ ((q15 & 7) << 3)];

    // ---- PV: o += P @ V, 8 MFMA
#pragma unroll
    for (int s = 0; s < 2; ++s)
#pragma unroll
      for (int nt = 0; nt < 4; ++nt) {
        int d = nt * 16 + q15;
        short8 b = *(short8*)&Vt[(d * 64 + s * 32 + dso) ^ ((d & 7) << 3)];
        o[nt] = MFMA16(pa[s], b, o[nt]);
      }
  }

  // ---- epilogue: normalize and store fp32
#pragma unroll
  for (int nt = 0; nt < 4; ++nt)
#pragma unroll
    for (int r = 0; r < 4; ++r) {
      int m = m0 + 16 * w + g * 4 + r;
      Ob[(size_t)m * Dn + nt * 16 + q15] = o[nt][r] / lrun[r];
    }
}

extern "C" void kernel_launch(void* const* d_in, const int* in_sizes, int n_in,
                              void* d_out, int out_size, void* d_ws, size_t ws_size,
                              hipStream_t stream) {
  (void)in_sizes; (void)n_in; (void)out_size; (void)d_ws; (void)ws_size;
  const float* Q  = (const float*)d_in[0];
  const float* K  = (const float*)d_in[1];
  const float* V  = (const float*)d_in[2];
  const float* PE = (const float*)d_in[3];
  float* Out = (float*)d_out;
  dim3 grid(512), block(256);
  hipLaunchKernelGGL(stair_attn, grid, block, 0, stream, Q, K, V, PE, Out);
}